// Round 2
// 497.517 us; speedup vs baseline: 1.0387x; 1.0387x over previous
//
#include <hip/hip_runtime.h>
#include <float.h>

#define BB 2048
#define KK 24
#define AA 2000
#define EPS_ 1e-8f

// clang native vector for __builtin_nontemporal_load (HIP float4 is a
// struct the builtin rejects; ext_vector_type is accepted and layout-
// compatible, with .x/.y/.z/.w swizzles).
typedef float v4f __attribute__((ext_vector_type(4)));

// Single-pass softmax (inputs ~N(0,1): exp never overflows; softmax is
// shift-invariant so skipping max-subtraction matches fp32 reference).
//
// Round-1 changes vs 514µs baseline:
//  - 256-thread blocks (4 waves x 6 rows) -> ~6 resident blocks/CU instead
//    of 4, more independent HBM streams, cheaper staging barrier coupling.
//  - nontemporal loads on the a_knns stream (393 MB, zero reuse): keeps the
//    emb rows (16 MB, reused by all 2048 blocks) resident in L3 instead of
//    being flushed every pass.
__global__ __launch_bounds__(256) void semantic_kernel(
    const float* __restrict__ a_knns,
    const float* __restrict__ emb,
    const int* __restrict__ aids,
    float* __restrict__ out)
{
    __shared__ __align__(16) float s_sim[AA];   // emb_pairs[aid] row, 8 KB
    __shared__ float s_scores[KK];

    const int b    = blockIdx.x;
    const int t    = threadIdx.x;
    const int lane = t & 63;
    const int wave = t >> 6;

    const int aid = aids[b];

    // Stage sim row into LDS: 500 float4, 2 coalesced rounds of 250 threads
    {
        const float4* __restrict__ esrc = (const float4*)(emb + (size_t)aid * AA);
        if (t < 250) {
            ((float4*)s_sim)[t]       = esrc[t];
            ((float4*)s_sim)[t + 250] = esrc[t + 250];
        }
    }
    __syncthreads();

    const float diag = s_sim[aid];

    // Each wave handles rows k = wave, wave+4, ..., wave+20  (6 rows)
    for (int k = wave; k < KK; k += 4) {
        const float* __restrict__ xrow =
            a_knns + ((size_t)b * KK + k) * AA;
        const v4f* __restrict__ xrow4 = (const v4f*)xrow;

        const float xa = xrow[aid];   // broadcast scalar load (L2-hot)

        float z = 0.0f, s = 0.0f;

        #pragma unroll
        for (int it = 0; it < 7; ++it) {
            const int i4 = it * 64 + lane;
            v4f    v  = __builtin_nontemporal_load(xrow4 + i4);
            float4 sv = ((const float4*)s_sim)[i4];
            float e0 = __expf(v.x);
            float e1 = __expf(v.y);
            float e2 = __expf(v.z);
            float e3 = __expf(v.w);
            z += (e0 + e1) + (e2 + e3);
            s += e0 * sv.x + e1 * sv.y + e2 * sv.z + e3 * sv.w;
        }
        {   // tail: i4 = 448 + lane, valid while < 500
            const int i4 = 448 + lane;
            if (i4 < AA / 4) {
                v4f    v  = __builtin_nontemporal_load(xrow4 + i4);
                float4 sv = ((const float4*)s_sim)[i4];
                float e0 = __expf(v.x);
                float e1 = __expf(v.y);
                float e2 = __expf(v.z);
                float e3 = __expf(v.w);
                z += (e0 + e1) + (e2 + e3);
                s += e0 * sv.x + e1 * sv.y + e2 * sv.z + e3 * sv.w;
            }
        }

        #pragma unroll
        for (int off = 32; off > 0; off >>= 1) {
            z += __shfl_xor(z, off);
            s += __shfl_xor(s, off);
        }

        if (lane == 0) {
            float nb_aid = __expf(xa) / z;
            float ws     = s / z - nb_aid * diag;
            float score  = 0.5f * ws - 0.5f * __logf(nb_aid + EPS_);
            s_scores[k]  = score;
        }
    }
    __syncthreads();

    // Softmax over K=24 per b, done by first wave
    if (t < 64) {
        float sc = (lane < KK) ? s_scores[lane] : -FLT_MAX;
        float mm = sc;
        #pragma unroll
        for (int off = 32; off > 0; off >>= 1)
            mm = fmaxf(mm, __shfl_xor(mm, off));
        float e  = (lane < KK) ? __expf(sc - mm) : 0.0f;
        float zz = e;
        #pragma unroll
        for (int off = 32; off > 0; off >>= 1)
            zz += __shfl_xor(zz, off);
        if (lane < KK)
            out[(size_t)b * KK + lane] = e / zz;
    }
}

extern "C" void kernel_launch(void* const* d_in, const int* in_sizes, int n_in,
                              void* d_out, int out_size, void* d_ws, size_t ws_size,
                              hipStream_t stream) {
    const float* a_knns = (const float*)d_in[0];
    const float* emb    = (const float*)d_in[1];
    const int*   aids   = (const int*)d_in[2];
    float*       out    = (float*)d_out;

    semantic_kernel<<<dim3(BB), dim3(256), 0, stream>>>(a_knns, emb, aids, out);
}